// Round 1
// baseline (1254.733 us; speedup 1.0000x reference)
//
#include <hip/hip_runtime.h>
#include <hip/hip_bf16.h>

#define SEQ   4096
#define EMB   2048
#define NH    16
#define NKV   4
#define HD    128

typedef short  bf16x8 __attribute__((ext_vector_type(8)));
typedef float  f32x4  __attribute__((ext_vector_type(4)));

__device__ __forceinline__ unsigned short f2b(float f) {
    unsigned int u = __float_as_uint(f);
    unsigned int r = u + 0x7fffu + ((u >> 16) & 1u);
    return (unsigned short)(r >> 16);
}

// ---------------- fp32 -> bf16 convert (vectorized) ----------------
__global__ void k_cvt_bf16(const float* __restrict__ in, unsigned short* __restrict__ out, int n) {
    int i = (blockIdx.x * blockDim.x + threadIdx.x) * 4;
    if (i >= n) return;
    float4 v = *(const float4*)(in + i);
    ushort4 o;
    o.x = f2b(v.x); o.y = f2b(v.y); o.z = f2b(v.z); o.w = f2b(v.w);
    *(ushort4*)(out + i) = o;
}

// ---------------- W (k,n) fp32 -> Wt (n,k) bf16 ----------------
__global__ void k_transpose_bf16(const float* __restrict__ W, unsigned short* __restrict__ Wt,
                                 int K, int N) {
    int tid = blockIdx.x * blockDim.x + threadIdx.x;
    int k = tid % K;
    int n = tid / K;
    if (n >= N) return;
    Wt[(size_t)n * K + k] = f2b(W[(size_t)k * N + n]);
}

// ---------------- generic bf16 GEMM: C(M,N) = A(M,K) * Bt(N,K)^T ----------------
// 128x128 tile, BK=64, 4 waves (2x2), each wave 64x64 via 4x4 16x16x32 MFMAs.
__global__ __launch_bounds__(256) void k_gemm_bf16(
    const unsigned short* __restrict__ A, const unsigned short* __restrict__ Bt,
    float* __restrict__ C, int M, int N, int K) {
    __shared__ unsigned short As[128][72];
    __shared__ unsigned short Bs[128][72];
    const int tid  = threadIdx.x;
    const int w    = tid >> 6, lane = tid & 63;
    const int wr   = w >> 1,   wc   = w & 1;
    const int lr   = lane & 15, lg  = lane >> 4;
    const int bx   = blockIdx.x, by = blockIdx.y;

    f32x4 acc[4][4] = {};
    const int nkt = K >> 6;
    for (int kt = 0; kt < nkt; ++kt) {
#pragma unroll
        for (int i = 0; i < 4; ++i) {
            int c   = tid + i * 256;
            int row = c >> 3, col = (c & 7) * 8;
            *(int4*)&As[row][col] = *(const int4*)(A  + (size_t)(by * 128 + row) * K + kt * 64 + col);
            *(int4*)&Bs[row][col] = *(const int4*)(Bt + (size_t)(bx * 128 + row) * K + kt * 64 + col);
        }
        __syncthreads();
#pragma unroll
        for (int kk = 0; kk < 2; ++kk) {
            bf16x8 a[4], b[4];
#pragma unroll
            for (int mi = 0; mi < 4; ++mi)
                a[mi] = *(const bf16x8*)&As[wr * 64 + mi * 16 + lr][kk * 32 + lg * 8];
#pragma unroll
            for (int ni = 0; ni < 4; ++ni)
                b[ni] = *(const bf16x8*)&Bs[wc * 64 + ni * 16 + lr][kk * 32 + lg * 8];
#pragma unroll
            for (int mi = 0; mi < 4; ++mi)
#pragma unroll
                for (int ni = 0; ni < 4; ++ni)
                    acc[mi][ni] = __builtin_amdgcn_mfma_f32_16x16x32_bf16(a[mi], b[ni], acc[mi][ni], 0, 0, 0);
        }
        __syncthreads();
    }
#pragma unroll
    for (int mi = 0; mi < 4; ++mi)
#pragma unroll
        for (int ni = 0; ni < 4; ++ni)
#pragma unroll
            for (int r = 0; r < 4; ++r) {
                int row = by * 128 + wr * 64 + mi * 16 + lg * 4 + r;
                int col = bx * 128 + wc * 64 + ni * 16 + lr;
                C[(size_t)row * N + col] = acc[mi][ni][r];
            }
}

// ---------------- RMSNorm + RoPE for Q: fp32 (s,2048) -> bf16 (h,s,d) ----------------
__global__ void k_qnorm_rope(const float* __restrict__ Qp, const int* __restrict__ pos,
                             const float* __restrict__ qw, unsigned short* __restrict__ Qb) {
    int row  = blockIdx.x * 4 + (threadIdx.x >> 6);   // over SEQ*NH
    int lane = threadIdx.x & 63;
    int s = row >> 4, h = row & 15;
    const float* src = Qp + (size_t)s * 2048 + h * 128;
    float x1 = src[lane], x2 = src[lane + 64];
    float ss = x1 * x1 + x2 * x2;
#pragma unroll
    for (int d = 1; d < 64; d <<= 1) ss += __shfl_xor(ss, d);
    float rs = rsqrtf(ss * (1.0f / 128.0f) + 1e-6f);
    float n1 = x1 * rs * qw[lane], n2 = x2 * rs * qw[lane + 64];
    float p = (float)pos[s];
    float freq = expf(-(float)lane * (9.210340371976184f / 64.0f)); // 10000^(-lane/64)
    float ang = p * freq;
    float sn, c;
    sincosf(ang, &sn, &c);
    float o1 = n1 * c - n2 * sn;
    float o2 = n2 * c + n1 * sn;
    unsigned short* dst = Qb + ((size_t)h * SEQ + s) * HD;
    dst[lane]      = f2b(o1);
    dst[lane + 64] = f2b(o2);
}

// ---------------- RMSNorm + RoPE for K: fp32 (s,512) -> bf16 (kv,s,d) + fp32 cache ----------------
__global__ void k_knorm_rope(const float* __restrict__ Kp, const int* __restrict__ pos,
                             const float* __restrict__ kw, unsigned short* __restrict__ Kb,
                             float* __restrict__ outK) {
    int row  = blockIdx.x * 4 + (threadIdx.x >> 6);   // over SEQ*NKV
    int lane = threadIdx.x & 63;
    int s = row >> 2, kv = row & 3;
    const float* src = Kp + (size_t)s * 512 + kv * 128;
    float x1 = src[lane], x2 = src[lane + 64];
    float ss = x1 * x1 + x2 * x2;
#pragma unroll
    for (int d = 1; d < 64; d <<= 1) ss += __shfl_xor(ss, d);
    float rs = rsqrtf(ss * (1.0f / 128.0f) + 1e-6f);
    float n1 = x1 * rs * kw[lane], n2 = x2 * rs * kw[lane + 64];
    float p = (float)pos[s];
    float freq = expf(-(float)lane * (9.210340371976184f / 64.0f));
    float ang = p * freq;
    float sn, c;
    sincosf(ang, &sn, &c);
    float o1 = n1 * c - n2 * sn;
    float o2 = n2 * c + n1 * sn;
    unsigned short* dst = Kb + ((size_t)kv * SEQ + s) * HD;
    float* od = outK + ((size_t)kv * SEQ + s) * HD;
    dst[lane]      = f2b(o1);
    dst[lane + 64] = f2b(o2);
    od[lane]       = o1;
    od[lane + 64]  = o2;
}

// ---------------- V pack: fp32 (s,512) -> bf16 V^T (kv,d,s) + fp32 cache (kv,s,d) ----------------
__global__ void k_vpack(const float* __restrict__ Vp, unsigned short* __restrict__ Vtb,
                        float* __restrict__ outV) {
    int tid = blockIdx.x * 256 + threadIdx.x;
    int s = tid >> 9, c = tid & 511;
    int kv = c >> 7, d = c & 127;
    float v = Vp[tid];
    Vtb[((size_t)kv * HD + d) * SEQ + s] = f2b(v);
    outV[((size_t)kv * SEQ + s) * HD + d] = v;
}

// ---------------- flash attention: Qb (h,s,d), Kb (kv,s,d), Vtb (kv,d,s) -> ctxb bf16 (s, h*128+d) ----------------
__global__ __launch_bounds__(256) void k_flash(
    const unsigned short* __restrict__ Qb, const unsigned short* __restrict__ Kb,
    const unsigned short* __restrict__ Vtb, unsigned short* __restrict__ ctxb) {
    __shared__ unsigned short Pl[4][16][72];
    const int h  = blockIdx.y, kv = h >> 2;
    const int qb = blockIdx.x * 64;
    const int w  = threadIdx.x >> 6, lane = threadIdx.x & 63;
    const int lr = lane & 15, lg = lane >> 4;

    const unsigned short* Qh = Qb + ((size_t)h * SEQ + qb + w * 16) * HD;
    bf16x8 aq[4];
#pragma unroll
    for (int kk = 0; kk < 4; ++kk)
        aq[kk] = *(const bf16x8*)(Qh + (size_t)lr * HD + kk * 32 + lg * 8);

    f32x4 O[8] = {};
    float m[4], l[4];
#pragma unroll
    for (int r = 0; r < 4; ++r) { m[r] = -1e30f; l[r] = 0.0f; }

    const int nt = blockIdx.x + 1;
    const unsigned short* Kh = Kb  + (size_t)kv * SEQ * HD;
    const unsigned short* Vh = Vtb + (size_t)kv * HD * SEQ;

    for (int t = 0; t < nt; ++t) {
        const int kvB = t * 64;
        f32x4 S[4];
#pragma unroll
        for (int ni = 0; ni < 4; ++ni) {
            f32x4 s = {};
#pragma unroll
            for (int kk = 0; kk < 4; ++kk) {
                bf16x8 bk = *(const bf16x8*)(Kh + (size_t)(kvB + ni * 16 + lr) * HD + kk * 32 + lg * 8);
                s = __builtin_amdgcn_mfma_f32_16x16x32_bf16(aq[kk], bk, s, 0, 0, 0);
            }
            S[ni] = s;
        }
        const float scale = 0.08838834764831845f;
        if (t == nt - 1) {
#pragma unroll
            for (int ni = 0; ni < 4; ++ni)
#pragma unroll
                for (int r = 0; r < 4; ++r) {
                    int key = kvB + ni * 16 + lr;
                    int q   = qb + w * 16 + lg * 4 + r;
                    S[ni][r] = (key > q) ? -1e30f : S[ni][r] * scale;
                }
        } else {
#pragma unroll
            for (int ni = 0; ni < 4; ++ni)
#pragma unroll
                for (int r = 0; r < 4; ++r) S[ni][r] *= scale;
        }
        // online softmax, per q-row (4 rows per lane, reduced across the 16-lane col group)
#pragma unroll
        for (int r = 0; r < 4; ++r) {
            float v = fmaxf(fmaxf(S[0][r], S[1][r]), fmaxf(S[2][r], S[3][r]));
#pragma unroll
            for (int d = 1; d < 16; d <<= 1) v = fmaxf(v, __shfl_xor(v, d));
            float mn = fmaxf(m[r], v);
            float al = __expf(m[r] - mn);
            m[r] = mn;
            float su = 0.0f;
#pragma unroll
            for (int ni = 0; ni < 4; ++ni) { float pp = __expf(S[ni][r] - mn); S[ni][r] = pp; su += pp; }
#pragma unroll
            for (int d = 1; d < 16; d <<= 1) su += __shfl_xor(su, d);
            l[r] = l[r] * al + su;
#pragma unroll
            for (int dt = 0; dt < 8; ++dt) O[dt][r] *= al;
        }
        // P -> LDS (re-shape C-layout into A-fragment layout)
#pragma unroll
        for (int ni = 0; ni < 4; ++ni)
#pragma unroll
            for (int r = 0; r < 4; ++r)
                Pl[w][lg * 4 + r][ni * 16 + lr] = f2b(S[ni][r]);
        __syncthreads();
#pragma unroll
        for (int kk = 0; kk < 2; ++kk) {
            bf16x8 pa = *(const bf16x8*)&Pl[w][lr][kk * 32 + lg * 8];
#pragma unroll
            for (int dt = 0; dt < 8; ++dt) {
                bf16x8 bv = *(const bf16x8*)(Vh + (size_t)(dt * 16 + lr) * SEQ + kvB + kk * 32 + lg * 8);
                O[dt] = __builtin_amdgcn_mfma_f32_16x16x32_bf16(pa, bv, O[dt], 0, 0, 0);
            }
        }
        __syncthreads();
    }
    // normalize + store ctx as bf16 (s, h*128+d)
#pragma unroll
    for (int r = 0; r < 4; ++r) {
        float inv = 1.0f / l[r];
        int row = qb + w * 16 + lg * 4 + r;
#pragma unroll
        for (int dt = 0; dt < 8; ++dt) {
            int col = h * HD + dt * 16 + lr;
            ctxb[(size_t)row * (NH * HD) + col] = f2b(O[dt][r] * inv);
        }
    }
}

extern "C" void kernel_launch(void* const* d_in, const int* in_sizes, int n_in,
                              void* d_out, int out_size, void* d_ws, size_t ws_size,
                              hipStream_t stream) {
    const float* x   = (const float*)d_in[0];
    const int*   pos = (const int*)d_in[1];
    // d_in[2] = attn_mask (pure causal; applied analytically, unused)
    const float* Wq  = (const float*)d_in[3];
    const float* Wk  = (const float*)d_in[4];
    const float* Wv  = (const float*)d_in[5];
    const float* Wo  = (const float*)d_in[6];
    const float* qw  = (const float*)d_in[7];
    const float* kw  = (const float*)d_in[8];

    float* out  = (float*)d_out;                       // (4096, 2048)
    float* outK = out + (size_t)SEQ * EMB;             // (4, 4096, 128)
    float* outV = outK + (size_t)NKV * SEQ * HD;       // (4, 4096, 128)

    char* ws = (char*)d_ws;
    float*          Qp   = (float*)(ws + 0);                      // 32 MB  (4096,2048)
    float*          Kp   = (float*)(ws + 33554432);               //  8 MB  (4096,512)
    float*          Vp   = (float*)(ws + 41943040);               //  8 MB  (4096,512)
    unsigned short* xb   = (unsigned short*)(ws + 50331648);      // 16 MB  (4096,2048)
    unsigned short* Wqt  = (unsigned short*)(ws + 67108864);      //  8 MB  (2048,2048)
    unsigned short* Wkt  = (unsigned short*)(ws + 75497472);      //  2 MB  (512,2048)
    unsigned short* Wvt  = (unsigned short*)(ws + 77594624);      //  2 MB  (512,2048)
    unsigned short* Wot  = (unsigned short*)(ws + 79691776);      //  8 MB  (2048,2048)
    unsigned short* Qb   = (unsigned short*)(ws + 88080384);      // 16 MB  (16,4096,128)
    unsigned short* Kb   = (unsigned short*)(ws + 104857600);     //  4 MB  (4,4096,128)
    unsigned short* Vtb  = (unsigned short*)(ws + 109051904);     //  4 MB  (4,128,4096)
    unsigned short* ctxb = (unsigned short*)(ws + 113246208);     // 16 MB  (4096,2048)

    k_cvt_bf16<<<8192, 256, 0, stream>>>(x, xb, SEQ * EMB);
    k_transpose_bf16<<<(2048 * 2048) / 256, 256, 0, stream>>>(Wq, Wqt, 2048, 2048);
    k_transpose_bf16<<<(2048 * 512)  / 256, 256, 0, stream>>>(Wk, Wkt, 2048, 512);
    k_transpose_bf16<<<(2048 * 512)  / 256, 256, 0, stream>>>(Wv, Wvt, 2048, 512);
    k_transpose_bf16<<<(2048 * 2048) / 256, 256, 0, stream>>>(Wo, Wot, 2048, 2048);

    k_gemm_bf16<<<dim3(16, 32), 256, 0, stream>>>(xb, Wqt, Qp, SEQ, 2048, 2048);
    k_gemm_bf16<<<dim3(4, 32),  256, 0, stream>>>(xb, Wkt, Kp, SEQ, 512, 2048);
    k_gemm_bf16<<<dim3(4, 32),  256, 0, stream>>>(xb, Wvt, Vp, SEQ, 512, 2048);

    k_qnorm_rope<<<(SEQ * NH) / 4, 256, 0, stream>>>(Qp, pos, qw, Qb);
    k_knorm_rope<<<(SEQ * NKV) / 4, 256, 0, stream>>>(Kp, pos, kw, Kb, outK);
    k_vpack<<<(SEQ * NKV * HD) / 256, 256, 0, stream>>>(Vp, Vtb, outV);

    k_flash<<<dim3(SEQ / 64, NH), 256, 0, stream>>>(Qb, Kb, Vtb, ctxb);

    k_gemm_bf16<<<dim3(16, 32), 256, 0, stream>>>(ctxb, Wot, out, SEQ, 2048, 2048);
}

// Round 3
// 846.603 us; speedup vs baseline: 1.4821x; 1.4821x over previous
//
#include <hip/hip_runtime.h>
#include <hip/hip_bf16.h>

#define SEQ   4096
#define EMB   2048
#define NH    16
#define NKV   4
#define HD    128

typedef short  bf16x8 __attribute__((ext_vector_type(8)));
typedef float  f32x4  __attribute__((ext_vector_type(4)));

__device__ __forceinline__ unsigned short f2b(float f) {
    unsigned int u = __float_as_uint(f);
    unsigned int r = u + 0x7fffu + ((u >> 16) & 1u);
    return (unsigned short)(r >> 16);
}

// ---------------- fp32 -> bf16 convert (vectorized) ----------------
__global__ void k_cvt_bf16(const float* __restrict__ in, unsigned short* __restrict__ out, int n) {
    int i = (blockIdx.x * blockDim.x + threadIdx.x) * 4;
    if (i >= n) return;
    float4 v = *(const float4*)(in + i);
    ushort4 o;
    o.x = f2b(v.x); o.y = f2b(v.y); o.z = f2b(v.z); o.w = f2b(v.w);
    *(ushort4*)(out + i) = o;
}

// ---------------- W (K,N) fp32 -> Wt (N,K) bf16, LDS-tiled 32x32 ----------------
__global__ __launch_bounds__(256) void k_transpose_bf16(const float* __restrict__ W,
                                                        unsigned short* __restrict__ Wt,
                                                        int K, int N) {
    __shared__ float t[32][33];
    const int bk = blockIdx.x * 32, bn = blockIdx.y * 32;
    const int col = threadIdx.x & 31, rq = threadIdx.x >> 5;
#pragma unroll
    for (int i = 0; i < 4; ++i) {
        int r = rq + i * 8;
        t[r][col] = W[(size_t)(bk + r) * N + bn + col];
    }
    __syncthreads();
#pragma unroll
    for (int i = 0; i < 4; ++i) {
        int r = rq + i * 8;
        Wt[(size_t)(bn + r) * K + bk + col] = f2b(t[col][r]);
    }
}

// ---------------- generic bf16 GEMM: C(M,N) = A(M,K) * Bt(N,K)^T ----------------
__global__ __launch_bounds__(256) void k_gemm_bf16(
    const unsigned short* __restrict__ A, const unsigned short* __restrict__ Bt,
    float* __restrict__ C, int M, int N, int K) {
    __shared__ unsigned short As[128][72];
    __shared__ unsigned short Bs[128][72];
    const int tid  = threadIdx.x;
    const int w    = tid >> 6, lane = tid & 63;
    const int wr   = w >> 1,   wc   = w & 1;
    const int lr   = lane & 15, lg  = lane >> 4;
    const int bx   = blockIdx.x, by = blockIdx.y;

    f32x4 acc[4][4] = {};
    const int nkt = K >> 6;
    for (int kt = 0; kt < nkt; ++kt) {
#pragma unroll
        for (int i = 0; i < 4; ++i) {
            int c   = tid + i * 256;
            int row = c >> 3, col = (c & 7) * 8;
            *(int4*)&As[row][col] = *(const int4*)(A  + (size_t)(by * 128 + row) * K + kt * 64 + col);
            *(int4*)&Bs[row][col] = *(const int4*)(Bt + (size_t)(bx * 128 + row) * K + kt * 64 + col);
        }
        __syncthreads();
#pragma unroll
        for (int kk = 0; kk < 2; ++kk) {
            bf16x8 a[4], b[4];
#pragma unroll
            for (int mi = 0; mi < 4; ++mi)
                a[mi] = *(const bf16x8*)&As[wr * 64 + mi * 16 + lr][kk * 32 + lg * 8];
#pragma unroll
            for (int ni = 0; ni < 4; ++ni)
                b[ni] = *(const bf16x8*)&Bs[wc * 64 + ni * 16 + lr][kk * 32 + lg * 8];
#pragma unroll
            for (int mi = 0; mi < 4; ++mi)
#pragma unroll
                for (int ni = 0; ni < 4; ++ni)
                    acc[mi][ni] = __builtin_amdgcn_mfma_f32_16x16x32_bf16(a[mi], b[ni], acc[mi][ni], 0, 0, 0);
        }
        __syncthreads();
    }
#pragma unroll
    for (int mi = 0; mi < 4; ++mi)
#pragma unroll
        for (int ni = 0; ni < 4; ++ni)
#pragma unroll
            for (int r = 0; r < 4; ++r) {
                int row = by * 128 + wr * 64 + mi * 16 + lg * 4 + r;
                int col = bx * 128 + wc * 64 + ni * 16 + lr;
                C[(size_t)row * N + col] = acc[mi][ni][r];
            }
}

// ---------------- RMSNorm + RoPE for Q: fp32 (s,2048) -> bf16 (h,s,d), attn scale folded in ----------------
__global__ void k_qnorm_rope(const float* __restrict__ Qp, const int* __restrict__ pos,
                             const float* __restrict__ qw, unsigned short* __restrict__ Qb) {
    int row  = blockIdx.x * 4 + (threadIdx.x >> 6);   // over SEQ*NH
    int lane = threadIdx.x & 63;
    int s = row >> 4, h = row & 15;
    const float* src = Qp + (size_t)s * 2048 + h * 128;
    float x1 = src[lane], x2 = src[lane + 64];
    float ss = x1 * x1 + x2 * x2;
#pragma unroll
    for (int d = 1; d < 64; d <<= 1) ss += __shfl_xor(ss, d);
    float rs = rsqrtf(ss * (1.0f / 128.0f) + 1e-6f);
    float n1 = x1 * rs * qw[lane], n2 = x2 * rs * qw[lane + 64];
    float p = (float)pos[s];
    float freq = expf(-(float)lane * (9.210340371976184f / 64.0f)); // 10000^(-lane/64)
    float ang = p * freq;
    float sn, c;
    sincosf(ang, &sn, &c);
    const float SC = 0.08838834764831845f;  // 1/sqrt(128), folded into Q
    float o1 = (n1 * c - n2 * sn) * SC;
    float o2 = (n2 * c + n1 * sn) * SC;
    unsigned short* dst = Qb + ((size_t)h * SEQ + s) * HD;
    dst[lane]      = f2b(o1);
    dst[lane + 64] = f2b(o2);
}

// ---------------- RMSNorm + RoPE for K: fp32 (s,512) -> bf16 (kv,s,d) + fp32 cache ----------------
__global__ void k_knorm_rope(const float* __restrict__ Kp, const int* __restrict__ pos,
                             const float* __restrict__ kw, unsigned short* __restrict__ Kb,
                             float* __restrict__ outK) {
    int row  = blockIdx.x * 4 + (threadIdx.x >> 6);   // over SEQ*NKV
    int lane = threadIdx.x & 63;
    int s = row >> 2, kv = row & 3;
    const float* src = Kp + (size_t)s * 512 + kv * 128;
    float x1 = src[lane], x2 = src[lane + 64];
    float ss = x1 * x1 + x2 * x2;
#pragma unroll
    for (int d = 1; d < 64; d <<= 1) ss += __shfl_xor(ss, d);
    float rs = rsqrtf(ss * (1.0f / 128.0f) + 1e-6f);
    float n1 = x1 * rs * kw[lane], n2 = x2 * rs * kw[lane + 64];
    float p = (float)pos[s];
    float freq = expf(-(float)lane * (9.210340371976184f / 64.0f));
    float ang = p * freq;
    float sn, c;
    sincosf(ang, &sn, &c);
    float o1 = n1 * c - n2 * sn;
    float o2 = n2 * c + n1 * sn;
    unsigned short* dst = Kb + ((size_t)kv * SEQ + s) * HD;
    float* od = outK + ((size_t)kv * SEQ + s) * HD;
    dst[lane]      = f2b(o1);
    dst[lane + 64] = f2b(o2);
    od[lane]       = o1;
    od[lane + 64]  = o2;
}

// ---------------- V pack: fp32 (s,512) -> bf16 V^T (kv,d,s) + fp32 cache (kv,s,d) ----------------
__global__ void k_vpack(const float* __restrict__ Vp, unsigned short* __restrict__ Vtb,
                        float* __restrict__ outV) {
    int tid = blockIdx.x * 256 + threadIdx.x;
    int s = tid >> 9, c = tid & 511;
    int kv = c >> 7, d = c & 127;
    float v = Vp[tid];
    Vtb[((size_t)kv * HD + d) * SEQ + s] = f2b(v);
    outV[((size_t)kv * SEQ + s) * HD + d] = v;
}

// ---------------- flash attention (swapped QK^T, no barriers, heavy-first) ----------------
// Qb (h,s,d) pre-scaled, Kb (kv,s,d), Vtb (kv,d,s) -> ctxb bf16 (s, h*128+d)
__global__ __launch_bounds__(256) void k_flash(
    const unsigned short* __restrict__ Qb, const unsigned short* __restrict__ Kb,
    const unsigned short* __restrict__ Vtb, unsigned short* __restrict__ ctxb) {
    __shared__ unsigned short Pl[4][16][80];   // per-wave private; stride 160B -> 4-way max
    const int bid = blockIdx.x;
    const int h  = bid & 15, kv = h >> 2;
    const int qt = 63 - (bid >> 4);            // heavy blocks launch first
    const int qb = qt * 64;
    const int w  = threadIdx.x >> 6, lane = threadIdx.x & 63;
    const int lr = lane & 15, lg = lane >> 4;

    // Q fragment (B-operand of swapped QK^T): lane holds Q row lr (q = qb + w*16 + lr)
    const unsigned short* Qh = Qb + ((size_t)h * SEQ + qb + w * 16) * HD;
    bf16x8 aq[4];
#pragma unroll
    for (int kk = 0; kk < 4; ++kk)
        aq[kk] = *(const bf16x8*)(Qh + (size_t)lr * HD + kk * 32 + lg * 8);

    f32x4 O[8] = {};
    float m = -1e30f, l = 0.0f;

    const int nt = qt + 1;
    const unsigned short* Kh = Kb  + (size_t)kv * SEQ * HD;
    const unsigned short* Vh = Vtb + (size_t)kv * HD * SEQ;

    for (int t = 0; t < nt; ++t) {
        const int kvB = t * 64;
        // S' = K * Q^T : lane holds col q=lr, rows = keys kvB + ni*16 + lg*4 + r
        f32x4 S[4];
#pragma unroll
        for (int ni = 0; ni < 4; ++ni) {
            f32x4 s = {};
#pragma unroll
            for (int kk = 0; kk < 4; ++kk) {
                bf16x8 bk = *(const bf16x8*)(Kh + (size_t)(kvB + ni * 16 + lr) * HD + kk * 32 + lg * 8);
                s = __builtin_amdgcn_mfma_f32_16x16x32_bf16(bk, aq[kk], s, 0, 0, 0);
            }
            S[ni] = s;
        }
        if (t == nt - 1) {
            const int q = qb + w * 16 + lr;
#pragma unroll
            for (int ni = 0; ni < 4; ++ni)
#pragma unroll
                for (int r = 0; r < 4; ++r) {
                    int key = kvB + ni * 16 + lg * 4 + r;
                    if (key > q) S[ni][r] = -1e30f;
                }
        }
        // per-q-row online softmax: this lane owns 16 of q=lr's 64 keys;
        // partner lanes are lr+16, lr+32, lr+48.
        float pmax = -1e30f;
#pragma unroll
        for (int ni = 0; ni < 4; ++ni)
#pragma unroll
            for (int r = 0; r < 4; ++r) pmax = fmaxf(pmax, S[ni][r]);
        pmax = fmaxf(pmax, __shfl_xor(pmax, 16));
        pmax = fmaxf(pmax, __shfl_xor(pmax, 32));
        float mn = fmaxf(m, pmax);
        float al = __expf(m - mn);
        m = mn;
        float su = 0.0f;
#pragma unroll
        for (int ni = 0; ni < 4; ++ni)
#pragma unroll
            for (int r = 0; r < 4; ++r) {
                float pp = __expf(S[ni][r] - mn);
                S[ni][r] = pp;
                su += pp;
            }
        su += __shfl_xor(su, 16);
        su += __shfl_xor(su, 32);
        l = l * al + su;

        // pack P (q-major) into per-wave LDS: row q=lr, cols = local key
#pragma unroll
        for (int ni = 0; ni < 4; ++ni) {
            unsigned int w0 = (unsigned int)f2b(S[ni][0]) | ((unsigned int)f2b(S[ni][1]) << 16);
            unsigned int w1 = (unsigned int)f2b(S[ni][2]) | ((unsigned int)f2b(S[ni][3]) << 16);
            *(unsigned int*)&Pl[w][lr][ni * 16 + lg * 4]     = w0;
            *(unsigned int*)&Pl[w][lr][ni * 16 + lg * 4 + 2] = w1;
        }
        // rescale O: O rows are q_local = lg*4 + r -> fetch al from lane q_local
        float alq[4];
#pragma unroll
        for (int r = 0; r < 4; ++r) alq[r] = __shfl(al, lg * 4 + r);
#pragma unroll
        for (int dt = 0; dt < 8; ++dt)
#pragma unroll
            for (int r = 0; r < 4; ++r) O[dt][r] *= alq[r];

        // PV: A = P (q x key), B = V^T (d rows over keys)  (wave-private LDS, no barrier)
#pragma unroll
        for (int kk = 0; kk < 2; ++kk) {
            bf16x8 pa = *(const bf16x8*)&Pl[w][lr][kk * 32 + lg * 8];
#pragma unroll
            for (int dt = 0; dt < 8; ++dt) {
                bf16x8 bv = *(const bf16x8*)(Vh + (size_t)(dt * 16 + lr) * SEQ + kvB + kk * 32 + lg * 8);
                O[dt] = __builtin_amdgcn_mfma_f32_16x16x32_bf16(pa, bv, O[dt], 0, 0, 0);
            }
        }
    }
    // normalize + store: O row q_local = lg*4+r needs l from lane q_local
#pragma unroll
    for (int r = 0; r < 4; ++r) {
        float li = __shfl(l, lg * 4 + r);
        float inv = 1.0f / li;
        int row = qb + w * 16 + lg * 4 + r;
#pragma unroll
        for (int dt = 0; dt < 8; ++dt) {
            int col = h * HD + dt * 16 + lr;
            ctxb[(size_t)row * (NH * HD) + col] = f2b(O[dt][r] * inv);
        }
    }
}

extern "C" void kernel_launch(void* const* d_in, const int* in_sizes, int n_in,
                              void* d_out, int out_size, void* d_ws, size_t ws_size,
                              hipStream_t stream) {
    const float* x   = (const float*)d_in[0];
    const int*   pos = (const int*)d_in[1];
    // d_in[2] = attn_mask (pure causal; applied analytically, unused)
    const float* Wq  = (const float*)d_in[3];
    const float* Wk  = (const float*)d_in[4];
    const float* Wv  = (const float*)d_in[5];
    const float* Wo  = (const float*)d_in[6];
    const float* qw  = (const float*)d_in[7];
    const float* kw  = (const float*)d_in[8];

    float* out  = (float*)d_out;                       // (4096, 2048)
    float* outK = out + (size_t)SEQ * EMB;             // (4, 4096, 128)
    float* outV = outK + (size_t)NKV * SEQ * HD;       // (4, 4096, 128)

    char* ws = (char*)d_ws;
    float*          Qp   = (float*)(ws + 0);                      // 32 MB  (4096,2048)
    float*          Kp   = (float*)(ws + 33554432);               //  8 MB  (4096,512)
    float*          Vp   = (float*)(ws + 41943040);               //  8 MB  (4096,512)
    unsigned short* xb   = (unsigned short*)(ws + 50331648);      // 16 MB  (4096,2048)
    unsigned short* Wqt  = (unsigned short*)(ws + 67108864);      //  8 MB  (2048,2048)
    unsigned short* Wkt  = (unsigned short*)(ws + 75497472);      //  2 MB  (512,2048)
    unsigned short* Wvt  = (unsigned short*)(ws + 77594624);      //  2 MB  (512,2048)
    unsigned short* Wot  = (unsigned short*)(ws + 79691776);      //  8 MB  (2048,2048)
    unsigned short* Qb   = (unsigned short*)(ws + 88080384);      // 16 MB  (16,4096,128)
    unsigned short* Kb   = (unsigned short*)(ws + 104857600);     //  4 MB  (4,4096,128)
    unsigned short* Vtb  = (unsigned short*)(ws + 109051904);     //  4 MB  (4,128,4096)
    unsigned short* ctxb = (unsigned short*)(ws + 113246208);     // 16 MB  (4096,2048)

    k_cvt_bf16<<<8192, 256, 0, stream>>>(x, xb, SEQ * EMB);
    k_transpose_bf16<<<dim3(64, 64), 256, 0, stream>>>(Wq, Wqt, 2048, 2048);
    k_transpose_bf16<<<dim3(64, 16), 256, 0, stream>>>(Wk, Wkt, 2048, 512);
    k_transpose_bf16<<<dim3(64, 16), 256, 0, stream>>>(Wv, Wvt, 2048, 512);
    k_transpose_bf16<<<dim3(64, 64), 256, 0, stream>>>(Wo, Wot, 2048, 2048);

    k_gemm_bf16<<<dim3(16, 32), 256, 0, stream>>>(xb, Wqt, Qp, SEQ, 2048, 2048);
    k_gemm_bf16<<<dim3(4, 32),  256, 0, stream>>>(xb, Wkt, Kp, SEQ, 512, 2048);
    k_gemm_bf16<<<dim3(4, 32),  256, 0, stream>>>(xb, Wvt, Vp, SEQ, 512, 2048);

    k_qnorm_rope<<<(SEQ * NH) / 4, 256, 0, stream>>>(Qp, pos, qw, Qb);
    k_knorm_rope<<<(SEQ * NKV) / 4, 256, 0, stream>>>(Kp, pos, kw, Kb, outK);
    k_vpack<<<(SEQ * NKV * HD) / 256, 256, 0, stream>>>(Vp, Vtb, outV);

    k_flash<<<1024, 256, 0, stream>>>(Qb, Kb, Vtb, ctxb);

    k_gemm_bf16<<<dim3(16, 32), 256, 0, stream>>>(ctxb, Wot, out, SEQ, 2048, 2048);
}